// Round 1
// baseline (596.429 us; speedup 1.0000x reference)
//
#include <hip/hip_runtime.h>
#include <hip/hip_bf16.h>

// Problem dims (compile-time constants)
#define NB   64
#define NH   64
#define NW   64
#define NCI  128
#define NCO  256
#define NHO  62
#define NWO  62
#define MTOT (NHO*NWO)   // 3844
#define KTOT (9*NCI)     // 1152

// GEMM tile config (m97-style: 128x128 tile, 4 waves, 4x4 16x16x32 MFMAs/wave)
#define BM  128
#define BN  128
#define BK  32
#define LDK 40   // padded LDS k-stride (elements): +16B pad -> conflict-free b128

using bf16x8 = __attribute__((ext_vector_type(8))) short;   // 8 bf16 = 4 VGPRs
using f32x4  = __attribute__((ext_vector_type(4))) float;

// ---------------------------------------------------------------------------
// Pass 1: X fp32 -> bf16 (64 MiB into ws). 8 elems/thread, 16B stores.
__global__ void cvt_x_kernel(const float* __restrict__ X,
                             __hip_bfloat16* __restrict__ Xb, int n8) {
    int i = blockIdx.x * 256 + threadIdx.x;
    if (i >= n8) return;
    const float4* p = (const float4*)X + (size_t)i * 2;
    float4 a = p[0], c = p[1];
    union { __hip_bfloat16 h[8]; float4 v; } u;
    u.h[0] = __float2bfloat16(a.x); u.h[1] = __float2bfloat16(a.y);
    u.h[2] = __float2bfloat16(a.z); u.h[3] = __float2bfloat16(a.w);
    u.h[4] = __float2bfloat16(c.x); u.h[5] = __float2bfloat16(c.y);
    u.h[6] = __float2bfloat16(c.z); u.h[7] = __float2bfloat16(c.w);
    *((float4*)Xb + i) = u.v;
}

// ---------------------------------------------------------------------------
// Pass 2: memWt[b][n][k] = bf16(W[k][n] * Werr[b][k][n])  (LDS-tiled transpose
// so both global read and global write are coalesced; k-contiguous output is
// what the MFMA B-fragment wants).
#define TK 64
#define TN 64
#define TPAD 65
__global__ void build_wt_kernel(const float* __restrict__ W,
                                const float* __restrict__ Werr,
                                __hip_bfloat16* __restrict__ Wt) {
    __shared__ __hip_bfloat16 tile[TK * TPAD];
    const int t  = threadIdx.x;
    const int b  = blockIdx.z;
    const int k0 = blockIdx.x * TK;
    const int n0 = blockIdx.y * TN;

    const int c4 = (t & 15) * 4;   // n offset within tile
    const int r  = t >> 4;         // k row within 16-row pass
    const float* wb = W + n0;
    const float* eb = Werr + (size_t)b * (KTOT * NCO) + n0;
#pragma unroll
    for (int p = 0; p < 4; p++) {
        int k  = k0 + r + p * 16;
        int kl = r + p * 16;
        float4 w = *(const float4*)(wb + (size_t)k * NCO + c4);
        float4 e = *(const float4*)(eb + (size_t)k * NCO + c4);
        tile[kl * TPAD + c4 + 0] = __float2bfloat16(w.x * e.x);
        tile[kl * TPAD + c4 + 1] = __float2bfloat16(w.y * e.y);
        tile[kl * TPAD + c4 + 2] = __float2bfloat16(w.z * e.z);
        tile[kl * TPAD + c4 + 3] = __float2bfloat16(w.w * e.w);
    }
    __syncthreads();
    // transposed write-out: thread -> (n' = t>>2, k-seg = (t&3)*16), 2x16B
    const int np = t >> 2;
    const int ks = (t & 3) * 16;
    __hip_bfloat16* ob = Wt + ((size_t)b * NCO + n0 + np) * KTOT + k0 + ks;
    union { __hip_bfloat16 h[8]; float4 v; } u;
#pragma unroll
    for (int h2 = 0; h2 < 2; h2++) {
#pragma unroll
        for (int q = 0; q < 8; q++) u.h[q] = tile[(ks + h2 * 8 + q) * TPAD + np];
        *(float4*)(ob + h2 * 8) = u.v;
    }
}

// ---------------------------------------------------------------------------
// Pass 3: per-sample implicit GEMM, bf16 MFMA 16x16x32.
// C[m,n] = sum_k A[m,k]*Wt[n,k];  m=(oh,ow) spatial, k=(kh,kw,ci).
// Block: 256 thr, 128x128 tile of sample b. Waves 2x2, each 64x64 (4x4 MFMA).
__global__ __launch_bounds__(256)
void gemm_bf16_kernel(const __hip_bfloat16* __restrict__ Xb,
                      const __hip_bfloat16* __restrict__ Wt,
                      const float* __restrict__ bias,
                      const float* __restrict__ Berr,
                      float* __restrict__ out) {
    __shared__ __hip_bfloat16 lds[(BM + BN) * LDK];   // 20 KiB
    __hip_bfloat16* As = lds;
    __hip_bfloat16* Bs = lds + BM * LDK;

    const int t  = threadIdx.x;
    const int b  = blockIdx.y;
    const int nt = blockIdx.x & 1;
    const int mt = blockIdx.x >> 1;
    const int m0 = mt * BM;
    const int n0 = nt * BN;

    // ---- staging map: thread t -> rows (t>>2, t>>2 + 64), 16B col seg t&3
    const int colA = (t & 3) * 8;     // element offset of 16B segment in BK row
    const int r0   = t >> 2;          // 0..63
    int mA0 = m0 + r0;       if (mA0 > MTOT - 1) mA0 = MTOT - 1;   // clamp edge
    int mA1 = m0 + r0 + 64;  if (mA1 > MTOT - 1) mA1 = MTOT - 1;
    const int oh0 = mA0 / NWO, ow0 = mA0 % NWO;
    const int oh1 = mA1 / NWO, ow1 = mA1 % NWO;
    const __hip_bfloat16* xbase = Xb + (size_t)b * (NH * NW * NCI);
    const int arow0 = (oh0 * NW + ow0) * NCI + colA;
    const int arow1 = (oh1 * NW + ow1) * NCI + colA;
    const __hip_bfloat16* wbase = Wt + ((size_t)b * NCO + n0) * KTOT;
    const int brow0 = r0 * KTOT + colA;
    const int brow1 = (r0 + 64) * KTOT + colA;

    // ---- fragment map
    const int lane = t & 63;
    const int wave = t >> 6;
    const int wm = wave & 1, wn = wave >> 1;
    const int lrow = lane & 15, quad = lane >> 4;
    const int aoff = (wm * 64 + lrow) * LDK + quad * 8;
    const int boff = (wn * 64 + lrow) * LDK + quad * 8;

    f32x4 acc[4][4];
#pragma unroll
    for (int i = 0; i < 4; i++)
#pragma unroll
        for (int j = 0; j < 4; j++) acc[i][j] = (f32x4){0.f, 0.f, 0.f, 0.f};

    for (int kk = 0; kk < KTOT; kk += BK) {
        // k-slice -> (kh,kw,ci0): BK=32 divides NCI=128, so slice stays in one (kh,kw)
        const int kh  = kk / (3 * NCI);
        const int kwp = (kk / NCI) % 3;
        const int ci0 = kk % NCI;
        const int ku  = (kh * NW + kwp) * NCI + ci0;   // X element offset (uniform)

        *(float4*)&As[r0 * LDK + colA]        = *(const float4*)(xbase + arow0 + ku);
        *(float4*)&As[(r0 + 64) * LDK + colA] = *(const float4*)(xbase + arow1 + ku);
        *(float4*)&Bs[r0 * LDK + colA]        = *(const float4*)(wbase + brow0 + kk);
        *(float4*)&Bs[(r0 + 64) * LDK + colA] = *(const float4*)(wbase + brow1 + kk);
        __syncthreads();

        bf16x8 af[4], bfr[4];
#pragma unroll
        for (int i = 0; i < 4; i++) af[i]  = *(const bf16x8*)&As[aoff + i * 16 * LDK];
#pragma unroll
        for (int j = 0; j < 4; j++) bfr[j] = *(const bf16x8*)&Bs[boff + j * 16 * LDK];
#pragma unroll
        for (int i = 0; i < 4; i++)
#pragma unroll
            for (int j = 0; j < 4; j++)
                acc[i][j] = __builtin_amdgcn_mfma_f32_16x16x32_bf16(
                    af[i], bfr[j], acc[i][j], 0, 0, 0);
        __syncthreads();
    }

    // ---- epilogue: + bias[n]*Berr[b][n]; C/D layout col=lane&15, row=quad*4+reg
    float bv[4];
#pragma unroll
    for (int j = 0; j < 4; j++) {
        int n = n0 + wn * 64 + j * 16 + lrow;
        bv[j] = bias[n] * Berr[b * NCO + n];
    }
#pragma unroll
    for (int i = 0; i < 4; i++) {
#pragma unroll
        for (int r = 0; r < 4; r++) {
            int m = m0 + wm * 64 + i * 16 + quad * 4 + r;
            if (m < MTOT) {
                float* op = out + ((size_t)b * MTOT + m) * NCO;
#pragma unroll
                for (int j = 0; j < 4; j++) {
                    int n = n0 + wn * 64 + j * 16 + lrow;
                    op[n] = acc[i][j][r] + bv[j];
                }
            }
        }
    }
}

// ---------------------------------------------------------------------------
// Safety net if ws is too small for the bf16 staging (~100 MiB): naive direct
// conv, correct but slow. Should never trigger on the real harness.
__global__ void naive_conv_kernel(const float* __restrict__ X,
                                  const float* __restrict__ W,
                                  const float* __restrict__ bias,
                                  const float* __restrict__ Werr,
                                  const float* __restrict__ Berr,
                                  float* __restrict__ out) {
    size_t idx = (size_t)blockIdx.x * 256 + threadIdx.x;
    if (idx >= (size_t)NB * MTOT * NCO) return;
    int n = idx % NCO;
    size_t m = idx / NCO;
    int ow = m % NWO; size_t t2 = m / NWO;
    int oh = t2 % NHO; int b = t2 / NHO;
    float acc = bias[n] * Berr[b * NCO + n];
    for (int kh = 0; kh < 3; kh++)
        for (int kw = 0; kw < 3; kw++) {
            const float* xp = X + (((size_t)b * NH + oh + kh) * NW + ow + kw) * NCI;
            const float* wp = W + ((kh * 3 + kw) * NCI) * (size_t)NCO + n;
            const float* ep = Werr + (size_t)b * KTOT * NCO + ((kh * 3 + kw) * NCI) * (size_t)NCO + n;
            for (int ci = 0; ci < NCI; ci++)
                acc += xp[ci] * wp[ci * NCO] * ep[ci * NCO];
        }
    out[idx] = acc;
}

// ---------------------------------------------------------------------------
extern "C" void kernel_launch(void* const* d_in, const int* in_sizes, int n_in,
                              void* d_out, int out_size, void* d_ws, size_t ws_size,
                              hipStream_t stream) {
    const float* X    = (const float*)d_in[0];
    const float* W    = (const float*)d_in[1];
    const float* bias = (const float*)d_in[2];
    const float* Werr = (const float*)d_in[3];
    const float* Berr = (const float*)d_in[4];
    float* out = (float*)d_out;

    const size_t xb_bytes = (size_t)NB * NH * NW * NCI * 2;   // 64 MiB
    const size_t wt_bytes = (size_t)NB * NCO * KTOT * 2;      // 36 MiB

    if (ws_size < xb_bytes + wt_bytes) {
        size_t total = (size_t)NB * MTOT * NCO;
        naive_conv_kernel<<<(int)((total + 255) / 256), 256, 0, stream>>>(
            X, W, bias, Werr, Berr, out);
        return;
    }

    __hip_bfloat16* Xb = (__hip_bfloat16*)d_ws;
    __hip_bfloat16* Wt = (__hip_bfloat16*)((char*)d_ws + xb_bytes);

    int n8 = NB * NH * NW * NCI / 8;                           // 4,194,304
    cvt_x_kernel<<<n8 / 256, 256, 0, stream>>>(X, Xb, n8);
    build_wt_kernel<<<dim3(KTOT / TK, NCO / TN, NB), 256, 0, stream>>>(W, Werr, Wt);
    gemm_bf16_kernel<<<dim3(2 * ((MTOT + BM - 1) / BM), NB), 256, 0, stream>>>(
        Xb, Wt, bias, Berr, out);
}

// Round 2
// 589.442 us; speedup vs baseline: 1.0119x; 1.0119x over previous
//
#include <hip/hip_runtime.h>
#include <hip/hip_bf16.h>

// Problem dims (compile-time constants)
#define NB   64
#define NH   64
#define NW   64
#define NCI  128
#define NCO  256
#define NHO  62
#define NWO  62
#define MTOT (NHO*NWO)   // 3844
#define KTOT (9*NCI)     // 1152

// GEMM tile config (m97-style: 128x128 tile, 4 waves, 4x4 16x16x32 MFMAs/wave)
#define BM  128
#define BN  128
#define BK  32   // bf16 elements; one LDS row = 64 B (bank-minimal for b128 frags)

using bf16x8 = __attribute__((ext_vector_type(8))) short;   // 8 bf16 = 4 VGPRs
using f32x4  = __attribute__((ext_vector_type(4))) float;

// async global->LDS, 16 B/lane; LDS dest = wave-uniform base + lane*16
__device__ __forceinline__ void gload_lds16(const __hip_bfloat16* g,
                                            __hip_bfloat16* l) {
    __builtin_amdgcn_global_load_lds(
        (const __attribute__((address_space(1))) unsigned int*)g,
        (__attribute__((address_space(3))) unsigned int*)l,
        16, 0, 0);
}

// ---------------------------------------------------------------------------
// Pass 1: X fp32 -> bf16 (64 MiB into ws). 8 elems/thread, 16B stores.
__global__ __launch_bounds__(256)
void cvt_x_kernel(const float* __restrict__ X,
                  __hip_bfloat16* __restrict__ Xb, int n8) {
    int i = blockIdx.x * 256 + threadIdx.x;
    if (i >= n8) return;
    const float4* p = (const float4*)X + (size_t)i * 2;
    float4 a = p[0], c = p[1];
    union { __hip_bfloat16 h[8]; float4 v; } u;
    u.h[0] = __float2bfloat16(a.x); u.h[1] = __float2bfloat16(a.y);
    u.h[2] = __float2bfloat16(a.z); u.h[3] = __float2bfloat16(a.w);
    u.h[4] = __float2bfloat16(c.x); u.h[5] = __float2bfloat16(c.y);
    u.h[6] = __float2bfloat16(c.z); u.h[7] = __float2bfloat16(c.w);
    *((float4*)Xb + i) = u.v;
}

// ---------------------------------------------------------------------------
// Pass 2: memWt[b][n][k] = bf16(W[k][n] * Werr[b][k][n])  (LDS-tiled transpose
// so both global read and global write are coalesced; k-contiguous output is
// what the MFMA B-fragment wants).
#define TK 64
#define TN 64
#define TPAD 65
__global__ __launch_bounds__(256)
void build_wt_kernel(const float* __restrict__ W,
                     const float* __restrict__ Werr,
                     __hip_bfloat16* __restrict__ Wt) {
    __shared__ __hip_bfloat16 tile[TK * TPAD];
    const int t  = threadIdx.x;
    const int b  = blockIdx.z;
    const int k0 = blockIdx.x * TK;
    const int n0 = blockIdx.y * TN;

    const int c4 = (t & 15) * 4;   // n offset within tile
    const int r  = t >> 4;         // k row within 16-row pass
    const float* wb = W + n0;
    const float* eb = Werr + (size_t)b * (KTOT * NCO) + n0;
#pragma unroll
    for (int p = 0; p < 4; p++) {
        int k  = k0 + r + p * 16;
        int kl = r + p * 16;
        float4 w = *(const float4*)(wb + (size_t)k * NCO + c4);
        float4 e = *(const float4*)(eb + (size_t)k * NCO + c4);
        tile[kl * TPAD + c4 + 0] = __float2bfloat16(w.x * e.x);
        tile[kl * TPAD + c4 + 1] = __float2bfloat16(w.y * e.y);
        tile[kl * TPAD + c4 + 2] = __float2bfloat16(w.z * e.z);
        tile[kl * TPAD + c4 + 3] = __float2bfloat16(w.w * e.w);
    }
    __syncthreads();
    // transposed write-out: thread -> (n' = t>>2, k-seg = (t&3)*16), 2x16B
    const int np = t >> 2;
    const int ks = (t & 3) * 16;
    __hip_bfloat16* ob = Wt + ((size_t)b * NCO + n0 + np) * KTOT + k0 + ks;
    union { __hip_bfloat16 h[8]; float4 v; } u;
#pragma unroll
    for (int h2 = 0; h2 < 2; h2++) {
#pragma unroll
        for (int q = 0; q < 8; q++) u.h[q] = tile[(ks + h2 * 8 + q) * TPAD + np];
        *(float4*)(ob + h2 * 8) = u.v;
    }
}

// ---------------------------------------------------------------------------
// Pass 3: per-sample implicit GEMM, bf16 MFMA 16x16x32, global_load_lds staging.
// C[m,n] = sum_k A[m,k]*Wt[n,k];  m=(oh,ow) spatial, k=(kh,kw,ci).
// Block: 256 thr, 128x128 tile of sample b. Waves 2x2, each 64x64 (4x4 MFMA).
__global__ __launch_bounds__(256)
void gemm_bf16_kernel(const __hip_bfloat16* __restrict__ Xb,
                      const __hip_bfloat16* __restrict__ Wt,
                      const float* __restrict__ bias,
                      const float* __restrict__ Berr,
                      float* __restrict__ out) {
    __shared__ __hip_bfloat16 As[BM * BK];   // 8 KiB
    __shared__ __hip_bfloat16 Bs[BN * BK];   // 8 KiB

    const int t    = threadIdx.x;
    const int lane = t & 63;
    const int wave = t >> 6;
    const int b  = blockIdx.y;
    const int nt = blockIdx.x & 1;
    const int mt = blockIdx.x >> 1;
    const int m0 = mt * BM;
    const int n0 = nt * BN;

    // ---- staging map (global_load_lds): wave w owns rows [w*32, w*32+32);
    // lane L covers (row = w*32 + part*16 + (L>>2), kseg = (L&3)*8), 16 B.
    const int seg = (lane & 3) * 8;   // element offset of 16B segment in BK row
    const int rl  = lane >> 2;        // 0..15
    const int rA0 = wave * 32 + rl;
    const int rA1 = rA0 + 16;

    int mA0 = m0 + rA0; if (mA0 > MTOT - 1) mA0 = MTOT - 1;   // clamp edge
    int mA1 = m0 + rA1; if (mA1 > MTOT - 1) mA1 = MTOT - 1;
    const int oh0 = mA0 / NWO, ow0 = mA0 % NWO;
    const int oh1 = mA1 / NWO, ow1 = mA1 % NWO;
    const __hip_bfloat16* xbase = Xb + (size_t)b * (NH * NW * NCI);
    const __hip_bfloat16* ga0 = xbase + (oh0 * NW + ow0) * NCI + seg;
    const __hip_bfloat16* ga1 = xbase + (oh1 * NW + ow1) * NCI + seg;
    const __hip_bfloat16* wbase = Wt + ((size_t)b * NCO + n0) * KTOT;
    const __hip_bfloat16* gb0 = wbase + rA0 * KTOT + seg;
    const __hip_bfloat16* gb1 = wbase + rA1 * KTOT + seg;

    __hip_bfloat16* lA0 = As + wave * (32 * BK);        // wave-uniform bases
    __hip_bfloat16* lA1 = lA0 + 16 * BK;
    __hip_bfloat16* lB0 = Bs + wave * (32 * BK);
    __hip_bfloat16* lB1 = lB0 + 16 * BK;

    // ---- fragment map
    const int wm = wave & 1, wn = wave >> 1;
    const int lrow = lane & 15, quad = lane >> 4;
    const int aoff = (wm * 64 + lrow) * BK + quad * 8;
    const int boff = (wn * 64 + lrow) * BK + quad * 8;

    f32x4 acc[4][4];
#pragma unroll
    for (int i = 0; i < 4; i++)
#pragma unroll
        for (int j = 0; j < 4; j++) acc[i][j] = (f32x4){0.f, 0.f, 0.f, 0.f};

    for (int kk = 0; kk < KTOT; kk += BK) {
        // k-slice -> (kh,kw,ci0): BK=32 divides NCI=128, so slice stays in one (kh,kw)
        const int kh  = kk / (3 * NCI);
        const int kwp = (kk / NCI) % 3;
        const int ci0 = kk % NCI;
        const int ku  = (kh * NW + kwp) * NCI + ci0;   // X element offset (uniform)

        gload_lds16(ga0 + ku, lA0);
        gload_lds16(ga1 + ku, lA1);
        gload_lds16(gb0 + kk, lB0);
        gload_lds16(gb1 + kk, lB1);
        __syncthreads();

        bf16x8 af[4], bfr[4];
#pragma unroll
        for (int i = 0; i < 4; i++) af[i]  = *(const bf16x8*)&As[aoff + i * 16 * BK];
#pragma unroll
        for (int j = 0; j < 4; j++) bfr[j] = *(const bf16x8*)&Bs[boff + j * 16 * BK];
#pragma unroll
        for (int i = 0; i < 4; i++)
#pragma unroll
            for (int j = 0; j < 4; j++)
                acc[i][j] = __builtin_amdgcn_mfma_f32_16x16x32_bf16(
                    af[i], bfr[j], acc[i][j], 0, 0, 0);
        __syncthreads();
    }

    // ---- epilogue: + bias[n]*Berr[b][n]; C/D layout col=lane&15, row=quad*4+reg
    float bv[4];
#pragma unroll
    for (int j = 0; j < 4; j++) {
        int n = n0 + wn * 64 + j * 16 + lrow;
        bv[j] = bias[n] * Berr[b * NCO + n];
    }
#pragma unroll
    for (int i = 0; i < 4; i++) {
#pragma unroll
        for (int r = 0; r < 4; r++) {
            int m = m0 + wm * 64 + i * 16 + quad * 4 + r;
            if (m < MTOT) {
                float* op = out + ((size_t)b * MTOT + m) * NCO;
#pragma unroll
                for (int j = 0; j < 4; j++) {
                    int n = n0 + wn * 64 + j * 16 + lrow;
                    op[n] = acc[i][j][r] + bv[j];
                }
            }
        }
    }
}

// ---------------------------------------------------------------------------
// Safety net if ws is too small for the bf16 staging (~100 MiB): naive direct
// conv, correct but slow. Should never trigger on the real harness.
__global__ void naive_conv_kernel(const float* __restrict__ X,
                                  const float* __restrict__ W,
                                  const float* __restrict__ bias,
                                  const float* __restrict__ Werr,
                                  const float* __restrict__ Berr,
                                  float* __restrict__ out) {
    size_t idx = (size_t)blockIdx.x * 256 + threadIdx.x;
    if (idx >= (size_t)NB * MTOT * NCO) return;
    int n = idx % NCO;
    size_t m = idx / NCO;
    int ow = m % NWO; size_t t2 = m / NWO;
    int oh = t2 % NHO; int b = t2 / NHO;
    float acc = bias[n] * Berr[b * NCO + n];
    for (int kh = 0; kh < 3; kh++)
        for (int kw = 0; kw < 3; kw++) {
            const float* xp = X + (((size_t)b * NH + oh + kh) * NW + ow + kw) * NCI;
            const float* wp = W + ((kh * 3 + kw) * NCI) * (size_t)NCO + n;
            const float* ep = Werr + (size_t)b * KTOT * NCO + ((kh * 3 + kw) * NCI) * (size_t)NCO + n;
            for (int ci = 0; ci < NCI; ci++)
                acc += xp[ci] * wp[ci * NCO] * ep[ci * NCO];
        }
    out[idx] = acc;
}

// ---------------------------------------------------------------------------
extern "C" void kernel_launch(void* const* d_in, const int* in_sizes, int n_in,
                              void* d_out, int out_size, void* d_ws, size_t ws_size,
                              hipStream_t stream) {
    const float* X    = (const float*)d_in[0];
    const float* W    = (const float*)d_in[1];
    const float* bias = (const float*)d_in[2];
    const float* Werr = (const float*)d_in[3];
    const float* Berr = (const float*)d_in[4];
    float* out = (float*)d_out;

    const size_t xb_bytes = (size_t)NB * NH * NW * NCI * 2;   // 64 MiB
    const size_t wt_bytes = (size_t)NB * NCO * KTOT * 2;      // 36 MiB

    if (ws_size < xb_bytes + wt_bytes) {
        size_t total = (size_t)NB * MTOT * NCO;
        naive_conv_kernel<<<(int)((total + 255) / 256), 256, 0, stream>>>(
            X, W, bias, Werr, Berr, out);
        return;
    }

    __hip_bfloat16* Xb = (__hip_bfloat16*)d_ws;
    __hip_bfloat16* Wt = (__hip_bfloat16*)((char*)d_ws + xb_bytes);

    int n8 = NB * NH * NW * NCI / 8;                           // 4,194,304
    cvt_x_kernel<<<n8 / 256, 256, 0, stream>>>(X, Xb, n8);
    build_wt_kernel<<<dim3(KTOT / TK, NCO / TN, NB), 256, 0, stream>>>(W, Werr, Wt);
    gemm_bf16_kernel<<<dim3(2 * ((MTOT + BM - 1) / BM), NB), 256, 0, stream>>>(
        Xb, Wt, bias, Berr, out);
}